// Round 7
// baseline (123.818 us; speedup 1.0000x reference)
//
#include <hip/hip_runtime.h>

#define CC 30                    // 5*NB + NC
#define TPW 32                   // cells per wave-tile
#define WPB 4                    // waves per block
#define TILE_FLOATS (TPW * CC)   // 960 floats = 3840 B per array per wave
#define TILE_VEC4   (TILE_FLOATS / 4)   // 240

// ---------------- main: wave-private LDS tiles, ZERO block barriers ----------------
__global__ __launch_bounds__(256) void yolo_main(
        const float* __restrict__ in,
        const float* __restrict__ tg,
        float* __restrict__ ws,
        int ncells, int nwaves_total, int pstride) {
    __shared__ float s_in[WPB * TILE_FLOATS];   // 15360 B
    __shared__ float s_tg[WPB * TILE_FLOATS];   // 15360 B

    const int tid   = threadIdx.x;
    const int lane  = tid & 63;
    const int wave  = tid >> 6;
    const int gwave = blockIdx.x * WPB + wave;

    float* lin = s_in + wave * TILE_FLOATS;     // this wave's private slice
    float* ltg = s_tg + wave * TILE_FLOATS;

    const int ntiles = (ncells + TPW - 1) / TPW;
    const float inv_gs = 0.14285714285714285f;  // 1/7 (abs err ~1e-7 vs 0.4 threshold)

    float a_boxes = 0.0f, a_conf = 0.0f, a_class = 0.0f;

    for (int tile = gwave; tile < ntiles; tile += nwaves_total) {
        const int cbase = tile * TPW;
        int n = ncells - cbase;
        if (n > TPW) n = TPW;

        // ---- Stage this wave's tile: lane-contiguous float4 (tile base 16B-aligned) ----
        if (n == TPW) {
            const float4* gin = (const float4*)(in + (size_t)cbase * CC);
            const float4* gtg = (const float4*)(tg + (size_t)cbase * CC);
            float4* vin = (float4*)lin;
            float4* vtg = (float4*)ltg;
            float4 bi[4], bt[4];
            // phase 1: issue all 8 independent global loads
            #pragma unroll
            for (int k = 0; k < 4; ++k) {
                const int idx = k * 64 + lane;
                if (idx < TILE_VEC4) { bi[k] = gin[idx]; bt[k] = gtg[idx]; }
            }
            // phase 2: LDS writes
            #pragma unroll
            for (int k = 0; k < 4; ++k) {
                const int idx = k * 64 + lane;
                if (idx < TILE_VEC4) { vin[idx] = bi[k]; vtg[idx] = bt[k]; }
            }
        } else {
            const int lim = n * CC;
            for (int k = lane; k < lim; k += 64) {
                lin[k] = in[(size_t)cbase * CC + k];
                ltg[k] = tg[(size_t)cbase * CC + k];
            }
        }
        // In-wave ordering only: producer == consumer wave. DS ops from one wave
        // complete in order; the fence stops compiler reordering across it.
        asm volatile("s_waitcnt vmcnt(0) lgkmcnt(0)" ::: "memory");
        __builtin_amdgcn_wave_barrier();

        // ---- Per-cell compute: cell = lane (only lanes < TPW active) ----
        if (lane < n) {
            // float2 LDS reads: record base = lane*120 B -> 8B-aligned for every lane.
            const float2* f2 = (const float2*)(lin + lane * CC);
            const float2* t2 = (const float2*)(ltg + lane * CC);

            const float2 fi0 = f2[0], fi1 = f2[1], fi2 = f2[2], fi3 = f2[3], fi4 = f2[4];
            const float2 tt0 = t2[0], tt1 = t2[1], tt2 = t2[2], tt4 = t2[4];

            const float conf_t = tt2.x;                  // t[4]
            const float coord  = (conf_t > 0.0f)  ? 1.0f : 0.0f;
            const float noobj  = (conf_t == 0.0f) ? 1.0f : 0.0f;

            const float d0 = fi2.x - tt2.x;              // f[4]-t[4]
            const float d1 = fi4.y - tt4.y;              // f[9]-t[9]
            const float l_noobj = noobj * (d0 * d0 + d1 * d1);

            const float bt0 = tt0.x, bt1 = tt0.y, bt2 = tt1.x, bt3 = tt1.y;
            const float ttx = bt0 * inv_gs, tty = bt1 * inv_gs;
            const float txmin = ttx - 0.5f * bt2, tymin = tty - 0.5f * bt3;
            const float txmax = ttx + 0.5f * bt2, tymax = tty + 0.5f * bt3;
            const float tarea = (txmax - txmin) * (tymax - tymin);

            const float px0 = fi0.x, py0 = fi0.y, pw0 = fi1.x, ph0 = fi1.y, pc0 = fi2.x;
            const float px1 = fi2.y, py1 = fi3.x, pw1 = fi3.y, ph1 = fi4.x, pc1 = fi4.y;

            float iou0, iou1;
            {
                const float cx = px0 * inv_gs, cy = py0 * inv_gs;
                const float xmin = cx - 0.5f * pw0, ymin = cy - 0.5f * ph0;
                const float xmax = cx + 0.5f * pw0, ymax = cy + 0.5f * ph0;
                const float wx = fmaxf(fminf(xmax, txmax) - fmaxf(xmin, txmin), 0.0f);
                const float wy = fmaxf(fminf(ymax, tymax) - fmaxf(ymin, tymin), 0.0f);
                const float inter = wx * wy;
                const float parea = (xmax - xmin) * (ymax - ymin);
                iou0 = inter / (parea + tarea - inter);
            }
            {
                const float cx = px1 * inv_gs, cy = py1 * inv_gs;
                const float xmin = cx - 0.5f * pw1, ymin = cy - 0.5f * ph1;
                const float xmax = cx + 0.5f * pw1, ymax = cy + 0.5f * ph1;
                const float wx = fmaxf(fminf(xmax, txmax) - fmaxf(xmin, txmin), 0.0f);
                const float wy = fmaxf(fminf(ymax, tymax) - fmaxf(ymin, tymin), 0.0f);
                const float inter = wx * wy;
                const float parea = (xmax - xmin) * (ymax - ymin);
                iou1 = inter / (parea + tarea - inter);
            }
            // jnp.argmax picks first max on ties -> strict > for box 1
            const bool  sel1    = iou1 > iou0;
            const float max_iou = fmaxf(iou0, iou1);

            const float rp0 = sel1 ? px1 : px0;
            const float rp1 = sel1 ? py1 : py0;
            const float rp2 = sel1 ? pw1 : pw0;
            const float rp3 = sel1 ? ph1 : ph0;
            const float rp4 = sel1 ? pc1 : pc0;

            const float dx = rp0 - bt0, dy = rp1 - bt1;
            const float sw = sqrtf(rp2) - sqrtf(bt2);
            const float sh = sqrtf(rp3) - sqrtf(bt3);
            const float dob = rp4 - max_iou;
            const float l_box = dx * dx + dy * dy + sw * sw + sh * sh;
            const float l_obj = dob * dob;

            // class loss: channels 10..29 = float2 indices 5..14
            float l_cls = 0.0f;
            #pragma unroll
            for (int j = 5; j < 15; ++j) {
                const float2 fv = f2[j];
                const float2 tv = t2[j];
                const float gx = fv.x - tv.x;
                const float gy = fv.y - tv.y;
                l_cls += gx * gx + gy * gy;
            }

            a_boxes += coord * l_box;
            a_conf  += coord * l_obj + 0.5f * l_noobj;
            a_class += coord * l_cls;
        }
        // keep next iteration's LDS writes behind this iteration's reads
        __builtin_amdgcn_wave_barrier();
    }

    // ---- wave-64 shuffle reduce; one partial triple per WAVE (no block reduce) ----
    #pragma unroll
    for (int off = 32; off > 0; off >>= 1) {
        a_boxes += __shfl_down(a_boxes, off, 64);
        a_conf  += __shfl_down(a_conf,  off, 64);
        a_class += __shfl_down(a_class, off, 64);
    }
    if (lane == 0) {
        ws[gwave]               = a_boxes;
        ws[gwave + pstride]     = a_conf;
        ws[gwave + 2 * pstride] = a_class;
    }
}

// ---------------- finalize: sum per-wave partials, scale, write out ----------------
__global__ __launch_bounds__(256) void yolo_finalize(
        const float* __restrict__ ws, float* __restrict__ out,
        int nparts, int pstride, float inv_bs) {
    float b = 0.0f, c = 0.0f, k = 0.0f;
    for (int i = threadIdx.x; i < nparts; i += 256) {
        b += ws[i];
        c += ws[i + pstride];
        k += ws[i + 2 * pstride];
    }
    #pragma unroll
    for (int off = 32; off > 0; off >>= 1) {
        b += __shfl_down(b, off, 64);
        c += __shfl_down(c, off, 64);
        k += __shfl_down(k, off, 64);
    }
    __shared__ float s_red[4][3];
    const int wave = threadIdx.x >> 6;
    if ((threadIdx.x & 63) == 0) {
        s_red[wave][0] = b;
        s_red[wave][1] = c;
        s_red[wave][2] = k;
    }
    __syncthreads();
    if (threadIdx.x == 0) {
        const float tb = s_red[0][0] + s_red[1][0] + s_red[2][0] + s_red[3][0];
        const float tc = s_red[0][1] + s_red[1][1] + s_red[2][1] + s_red[3][1];
        const float tk = s_red[0][2] + s_red[1][2] + s_red[2][2] + s_red[3][2];
        out[0] = 0.5f * tb * inv_bs;   // LAMBDA_COORD*(xy+wh)/bs
        out[1] = tc * inv_bs;          // (obj + 0.5*noobj)/bs
        out[2] = tk * inv_bs;          // class/bs
    }
}

extern "C" void kernel_launch(void* const* d_in, const int* in_sizes, int n_in,
                              void* d_out, int out_size, void* d_ws, size_t ws_size,
                              hipStream_t stream) {
    const float* in = (const float*)d_in[0];
    const float* tg = (const float*)d_in[1];
    float* out = (float*)d_out;
    float* ws  = (float*)d_ws;

    const int ncells = in_sizes[0] / CC;          // B * 49
    const int B = ncells / 49;
    const float inv_bs = 1.0f / (float)B;

    // 30.7 KB LDS/block -> up to 5 blocks/CU by LDS; VGPR likely caps at 4.
    // Oversubscribed persistent grid is safe (no inter-block sync).
    const int nblocks = 1280;
    const int nwaves  = nblocks * WPB;
    const int pstride = nwaves;

    yolo_main<<<nblocks, 256, 0, stream>>>(in, tg, ws, ncells, nwaves, pstride);
    yolo_finalize<<<1, 256, 0, stream>>>(ws, out, nwaves, pstride, inv_bs);
}